// Round 17
// baseline (255.815 us; speedup 1.0000x reference)
//
#include <hip/hip_runtime.h>
#include <cmath>

#define SEQ 1600
#define NB  1024
#define H   12
#define PP  8

typedef float f2 __attribute__((ext_vector_type(2)));

// ---- param block offsets (floats) ----
#define O_G0A  0      // 8 x f2
#define O_G0B  16
#define O_G0C  32
#define O_G1A  48
#define O_G1B  64
#define O_G2A  80
#define O_G2B  96
#define O_LB0R 112    // 8 x f2 (lbr,lbr)
#define O_LB0I 128
#define O_LB1R 144
#define O_LB1I 160
#define O_LB2R 176
#define O_LB2I 192
#define O_C0R  208    // 48 x f2 (2*cre_h, 2*cre_h1), idx h2*8+p
#define O_C0I  304    // 48 x f2 (-2*cim_h, -2*cim_h1)
#define O_C1R  400
#define O_C1I  496
#define O_BB1  592    // 96 x f2 (re,im), idx h*8+p
#define O_BB2  784
#define O_FX0  976    // 6 x f2 h-pairs
#define O_FY0  988
#define O_FZ0  1000
#define O_FW0  1012
#define O_F1X  1024
#define O_F1Y  1036
#define O_F1Z  1048
#define O_CWN  1060   // 8 x f2 (2*re, -2*im)
#define O_A6   1076   // 24 x float2
#define O_A7   1124
#define O_SC   1172   // 2 floats
#define PRMF   1174

// r0 stash: [b][j][q][tid] float4 planes, j<7, q<3, tid<256 (round-8 proven layout)
__device__ __forceinline__ size_t r0base(int b, int j, int tid) {
    return (((size_t)b * 7 + j) * 3) * 256 + tid;
}

// ---- packed fp32 helpers ----
__device__ __forceinline__ f2 pk_fma_s(f2 a_s, f2 b, f2 c) {
    double d;
    asm("v_pk_fma_f32 %0, %1, %2, %3"
        : "=v"(d)
        : "s"(__builtin_bit_cast(double, a_s)),
          "v"(__builtin_bit_cast(double, b)),
          "v"(__builtin_bit_cast(double, c)));
    return __builtin_bit_cast(f2, d);
}
__device__ __forceinline__ f2 pk_fma_s_blo(f2 a_s, f2 b, f2 c) {
    double d;
    asm("v_pk_fma_f32 %0, %1, %2, %3 op_sel:[0,0,0] op_sel_hi:[1,0,1]"
        : "=v"(d)
        : "s"(__builtin_bit_cast(double, a_s)),
          "v"(__builtin_bit_cast(double, b)),
          "v"(__builtin_bit_cast(double, c)));
    return __builtin_bit_cast(f2, d);
}
__device__ __forceinline__ f2 pk_fma_s_bhi(f2 a_s, f2 b, f2 c) {
    double d;
    asm("v_pk_fma_f32 %0, %1, %2, %3 op_sel:[0,1,0] op_sel_hi:[1,1,1]"
        : "=v"(d)
        : "s"(__builtin_bit_cast(double, a_s)),
          "v"(__builtin_bit_cast(double, b)),
          "v"(__builtin_bit_cast(double, c)));
    return __builtin_bit_cast(f2, d);
}
__device__ __forceinline__ f2 pk_add_s(f2 a_s, f2 b) {
    double d;
    asm("v_pk_add_f32 %0, %1, %2"
        : "=v"(d)
        : "s"(__builtin_bit_cast(double, a_s)),
          "v"(__builtin_bit_cast(double, b)));
    return __builtin_bit_cast(f2, d);
}
__device__ __forceinline__ f2 pk_add_vv(f2 a, f2 b) {
    double d;
    asm("v_pk_add_f32 %0, %1, %2"
        : "=v"(d)
        : "v"(__builtin_bit_cast(double, a)),
          "v"(__builtin_bit_cast(double, b)));
    return __builtin_bit_cast(f2, d);
}
// s' = (lbr + i*lbi) * s + bu
__device__ __forceinline__ f2 cfma_state(f2 s, f2 lbr2_s, f2 lbi2_s, f2 bu) {
    double t, d;
    asm("v_pk_fma_f32 %0, %1, %2, %3 op_sel:[1,0,0] op_sel_hi:[0,1,1] neg_lo:[1,0,0]"
        : "=v"(t)
        : "v"(__builtin_bit_cast(double, s)),
          "s"(__builtin_bit_cast(double, lbi2_s)),
          "v"(__builtin_bit_cast(double, bu)));
    asm("v_pk_fma_f32 %0, %1, %2, %3"
        : "=v"(d)
        : "v"(__builtin_bit_cast(double, s)),
          "s"(__builtin_bit_cast(double, lbr2_s)),
          "v"(t));
    return __builtin_bit_cast(f2, d);
}

// ---------------- BN stats ----------------
__global__ __launch_bounds__(256) void k_stats1(const float* __restrict__ x,
                                                float* __restrict__ pS,
                                                float* __restrict__ pQ) {
    int l = blockIdx.x * 256 + threadIdx.x;
    if (l >= SEQ) return;
    int b0 = blockIdx.y * 64;
    float s = 0.f, q = 0.f;
    for (int b = 0; b < 64; ++b) {
        float v = x[(size_t)(b0 + b) * SEQ + l];
        s += v; q += v * v;
    }
    pS[blockIdx.y * SEQ + l] = s;
    pQ[blockIdx.y * SEQ + l] = q;
}

__global__ __launch_bounds__(256) void k_stats2(const float* __restrict__ pS,
                                                const float* __restrict__ pQ,
                                                const float* __restrict__ w1,
                                                const float* __restrict__ b1,
                                                const float* __restrict__ gam,
                                                const float* __restrict__ bet,
                                                float* __restrict__ scale,
                                                float* __restrict__ shift) {
    int l = blockIdx.x * 256 + threadIdx.x;
    if (l >= SEQ) return;
    float wm = 0, wq = 0, wb = 0, bm = 0, bq = 0;
    for (int h = 0; h < H; h++) {
        float w = w1[h], b = b1[h];
        wm += w; wq += w * w; wb += w * b; bm += b; bq += b * b;
    }
    const float inv = 1.f / 12.f;
    wm *= inv; wq *= inv; wb *= inv; bm *= inv; bq *= inv;
    float s = 0, q = 0;
    for (int k = 0; k < 16; k++) { s += pS[k * SEQ + l]; q += pQ[k * SEQ + l]; }
    float ex = s * (1.f / NB), exx = q * (1.f / NB);
    float mean = ex * wm + bm;
    float e2   = exx * wq + 2.f * ex * wb + bq;
    float var  = e2 - mean * mean;
    float sc   = gam[l] * rsqrtf(var + 1e-5f);
    scale[l] = sc;
    shift[l] = bet[l] - mean * sc;
}

// ---------------- one-time derived parameters ----------------
__global__ void k_prep(const float* __restrict__ l1w, const float* __restrict__ l1b,
                       const float* __restrict__ l2w, const float* __restrict__ l2b,
                       const float* __restrict__ lamr, const float* __restrict__ lami,
                       const float* __restrict__ bre, const float* __restrict__ bim,
                       const float* __restrict__ cre, const float* __restrict__ cim,
                       const float* __restrict__ dv,  const float* __restrict__ lstep,
                       float* __restrict__ gprm) {
    const int t = threadIdx.x;
    if (t < 48) {   // C matrices as h-pair tables, pre-scaled by 2
        int h2 = t >> 3, p = t & 7, h = 2 * h2;
        gprm[O_C0R + 2 * t]     = 2.f * cre[h * PP + p];
        gprm[O_C0R + 2 * t + 1] = 2.f * cre[(h + 1) * PP + p];
        gprm[O_C0I + 2 * t]     = -2.f * cim[h * PP + p];
        gprm[O_C0I + 2 * t + 1] = -2.f * cim[(h + 1) * PP + p];
        gprm[O_C1R + 2 * t]     = 2.f * cre[96 + h * PP + p];
        gprm[O_C1R + 2 * t + 1] = 2.f * cre[96 + (h + 1) * PP + p];
        gprm[O_C1I + 2 * t]     = -2.f * cim[96 + h * PP + p];
        gprm[O_C1I + 2 * t + 1] = -2.f * cim[96 + (h + 1) * PP + p];
    }
    if (t < 6) {    // finish tables as h-pairs
        int h = 2 * t;
        gprm[O_FX0 + 2 * t] = l1w[h] * dv[h];         gprm[O_FX0 + 2 * t + 1] = l1w[h + 1] * dv[h + 1];
        gprm[O_FY0 + 2 * t] = l1b[h] * dv[h];         gprm[O_FY0 + 2 * t + 1] = l1b[h + 1] * dv[h + 1];
        gprm[O_FZ0 + 2 * t] = dv[h];                  gprm[O_FZ0 + 2 * t + 1] = dv[h + 1];
        gprm[O_FW0 + 2 * t] = l1w[h] * dv[H + h];     gprm[O_FW0 + 2 * t + 1] = l1w[h + 1] * dv[H + h + 1];
        gprm[O_F1X + 2 * t] = l1b[h] * dv[H + h];     gprm[O_F1X + 2 * t + 1] = l1b[h + 1] * dv[H + h + 1];
        gprm[O_F1Y + 2 * t] = dv[H + h];              gprm[O_F1Y + 2 * t + 1] = dv[H + h + 1];
        gprm[O_F1Z + 2 * t] = l2w[h] * dv[2 * H + h]; gprm[O_F1Z + 2 * t + 1] = l2w[h + 1] * dv[2 * H + h + 1];
    }
    if (t == 0) {
        float s0 = l2b[0], s1 = 0.f;
        for (int h = 0; h < H; h++) {
            float dw = l2w[h] * dv[2 * H + h];
            s0 += l1b[h] * dw; s1 += l1w[h] * dw;
        }
        gprm[O_SC + 0] = s0; gprm[O_SC + 1] = s1;
    }
    if (t < 24) {
        int L = t >> 3, p = t & 7;
        float stp = expf(lstep[L * PP + p]);
        float lr = lamr[L * PP + p], li = lami[L * PP + p];
        float er = expf(lr * stp);
        float lbr = er * cosf(li * stp), lbi = er * sinf(li * stp);   // lam_bar
        float p2r = lbr * lbr - lbi * lbi, p2i = 2.f * lbr * lbi;
        float p4r = p2r * p2r - p2i * p2i, p4i = 2.f * p2r * p2i;
        float p6r = p4r * p2r - p4i * p2i, p6i = p4r * p2i + p4i * p2r;
        float p7r = p6r * lbr - p6i * lbi, p7i = p6r * lbi + p6i * lbr;
        gprm[O_A6 + 2 * (L * PP + p) + 0] = p6r;
        gprm[O_A6 + 2 * (L * PP + p) + 1] = p6i;
        gprm[O_A7 + 2 * (L * PP + p) + 0] = p7r;
        gprm[O_A7 + 2 * (L * PP + p) + 1] = p7i;
        float den = lr * lr + li * li;
        float fr = ((lbr - 1.f) * lr + lbi * li) / den;
        float fi = (lbi * lr - (lbr - 1.f) * li) / den;
        float sAr = 0, sAi = 0, sBr = 0, sBi = 0, sCr = 0, sCi = 0;
        for (int h = 0; h < H; h++) {
            float brr = bre[L * 96 + p * H + h], bii = bim[L * 96 + p * H + h];
            float vr = fr * brr - fi * bii, vi = fr * bii + fi * brr;  // b_bar[p,h]
            float w = l1w[h], bb = l1b[h];
            sAr += w * vr; sAi += w * vi; sBr += bb * vr; sBi += bb * vi; sCr += vr; sCi += vi;
            int fidx = 2 * (h * PP + p);
            if (L == 1)      { gprm[O_BB1 + fidx] = vr; gprm[O_BB1 + fidx + 1] = vi; }
            else if (L == 2) { gprm[O_BB2 + fidx] = vr; gprm[O_BB2 + fidx + 1] = vi; }
        }
        if (L == 0) {
            gprm[O_G0A + 2 * p] = sAr; gprm[O_G0A + 2 * p + 1] = sAi;
            gprm[O_G0B + 2 * p] = sBr; gprm[O_G0B + 2 * p + 1] = sBi;
            gprm[O_G0C + 2 * p] = sCr; gprm[O_G0C + 2 * p + 1] = sCi;
            gprm[O_LB0R + 2 * p] = lbr; gprm[O_LB0R + 2 * p + 1] = lbr;
            gprm[O_LB0I + 2 * p] = lbi; gprm[O_LB0I + 2 * p + 1] = lbi;
        } else if (L == 1) {
            gprm[O_G1A + 2 * p] = sAr; gprm[O_G1A + 2 * p + 1] = sAi;
            gprm[O_G1B + 2 * p] = sBr; gprm[O_G1B + 2 * p + 1] = sBi;
            gprm[O_LB1R + 2 * p] = lbr; gprm[O_LB1R + 2 * p + 1] = lbr;
            gprm[O_LB1I + 2 * p] = lbi; gprm[O_LB1I + 2 * p + 1] = lbi;
        } else {
            gprm[O_G2A + 2 * p] = sAr; gprm[O_G2A + 2 * p + 1] = sAi;
            gprm[O_G2B + 2 * p] = sBr; gprm[O_G2B + 2 * p + 1] = sBi;
            gprm[O_LB2R + 2 * p] = lbr; gprm[O_LB2R + 2 * p + 1] = lbr;
            gprm[O_LB2I + 2 * p] = lbi; gprm[O_LB2I + 2 * p + 1] = lbi;
            float swr = 0, swi = 0;
            for (int hh = 0; hh < H; hh++) {
                float wv = l2w[hh];
                swr += wv * cre[192 + hh * PP + p];
                swi += wv * cim[192 + hh * PP + p];
            }
            gprm[O_CWN + 2 * p + 0] = 2.f * swr; gprm[O_CWN + 2 * p + 1] = -2.f * swi;
        }
    }
}

// ---- hierarchical carry scan across 256 threads (f2 states) ----
__device__ __forceinline__ void scan_carry256(f2* S, const float2* a_init,
                                              int lane, int w,
                                              float2 (*aggA)[PP], float2 (*aggS)[PP]) {
    f2 A[PP];
#pragma unroll
    for (int p = 0; p < PP; p++) { A[p].x = a_init[p].x; A[p].y = a_init[p].y; }
#pragma unroll
    for (int d = 1; d < 64; d <<= 1) {
#pragma unroll
        for (int p = 0; p < PP; p++) {
            float fSr = __shfl_up(S[p].x, (unsigned)d, 64);
            float fSi = __shfl_up(S[p].y, (unsigned)d, 64);
            float fAr = __shfl_up(A[p].x, (unsigned)d, 64);
            float fAi = __shfl_up(A[p].y, (unsigned)d, 64);
            if (lane >= d) {
                float nsr = A[p].x * fSr - A[p].y * fSi + S[p].x;
                float nsi = A[p].x * fSi + A[p].y * fSr + S[p].y;
                float nar = fAr * A[p].x - fAi * A[p].y;
                float nai = fAr * A[p].y + fAi * A[p].x;
                S[p].x = nsr; S[p].y = nsi; A[p].x = nar; A[p].y = nai;
            }
        }
    }
    __syncthreads();
    if (lane == 63) {
#pragma unroll
        for (int p = 0; p < PP; p++) {
            aggA[w][p] = make_float2(A[p].x, A[p].y);
            aggS[w][p] = make_float2(S[p].x, S[p].y);
        }
    }
    __syncthreads();
    float eSr[PP], eSi[PP], eAr[PP], eAi[PP];
#pragma unroll
    for (int p = 0; p < PP; p++) {
        float sr = __shfl_up(S[p].x, 1u, 64);
        float si = __shfl_up(S[p].y, 1u, 64);
        float ar = __shfl_up(A[p].x, 1u, 64);
        float ai = __shfl_up(A[p].y, 1u, 64);
        eSr[p] = (lane > 0) ? sr : 0.f;
        eSi[p] = (lane > 0) ? si : 0.f;
        eAr[p] = (lane > 0) ? ar : 1.f;
        eAi[p] = (lane > 0) ? ai : 0.f;
    }
    float Pr[PP], Pi[PP];
#pragma unroll
    for (int p = 0; p < PP; p++) { Pr[p] = 0.f; Pi[p] = 0.f; }
    for (int w2 = 0; w2 < w; w2++) {
#pragma unroll
        for (int p = 0; p < PP; p++) {
            float2 a = aggA[w2][p];
            float2 s = aggS[w2][p];
            float nr = a.x * Pr[p] - a.y * Pi[p] + s.x;
            float ni = a.x * Pi[p] + a.y * Pr[p] + s.y;
            Pr[p] = nr; Pi[p] = ni;
        }
    }
#pragma unroll
    for (int p = 0; p < PP; p++) {
        S[p].x = eAr[p] * Pr[p] - eAi[p] * Pi[p] + eSr[p];
        S[p].y = eAr[p] * Pi[p] + eAi[p] * Pr[p] + eSi[p];
    }
}

// ---------------- fully fused: 3 layers, h-pair packed fp32, r0 stashed ----------------
__global__ __launch_bounds__(256)
void k_main(const float* __restrict__ x,
            const float* __restrict__ gprm,
            const float* __restrict__ g_scale, const float* __restrict__ g_shift,
            float* __restrict__ r0buf,
            float* __restrict__ out) {
    __shared__ float xl[SEQ], scl[SEQ], shl[SEQ];
    __shared__ float2 aggA[4][PP], aggS[4][PP];
    const int tid = threadIdx.x, b = blockIdx.x;
    for (int i = tid; i < SEQ; i += 256) {
        xl[i] = x[(size_t)b * SEQ + i];
        scl[i] = g_scale[i];
        shl[i] = g_shift[i];
    }
    __syncthreads();
    const f2* g0a = (const f2*)(gprm + O_G0A);
    const f2* g0b = (const f2*)(gprm + O_G0B);
    const f2* g0c = (const f2*)(gprm + O_G0C);
    const f2* g1a = (const f2*)(gprm + O_G1A);
    const f2* g1b = (const f2*)(gprm + O_G1B);
    const f2* g2a = (const f2*)(gprm + O_G2A);
    const f2* g2b = (const f2*)(gprm + O_G2B);
    const f2* lb0r = (const f2*)(gprm + O_LB0R);
    const f2* lb0i = (const f2*)(gprm + O_LB0I);
    const f2* lb1r = (const f2*)(gprm + O_LB1R);
    const f2* lb1i = (const f2*)(gprm + O_LB1I);
    const f2* lb2r = (const f2*)(gprm + O_LB2R);
    const f2* lb2i = (const f2*)(gprm + O_LB2I);
    const f2* c0r = (const f2*)(gprm + O_C0R);
    const f2* c0i = (const f2*)(gprm + O_C0I);
    const f2* c1r = (const f2*)(gprm + O_C1R);
    const f2* c1i = (const f2*)(gprm + O_C1I);
    const f2* bb1 = (const f2*)(gprm + O_BB1);
    const f2* bb2 = (const f2*)(gprm + O_BB2);
    const f2* fx0 = (const f2*)(gprm + O_FX0);
    const f2* fy0 = (const f2*)(gprm + O_FY0);
    const f2* fz0 = (const f2*)(gprm + O_FZ0);
    const f2* fw0 = (const f2*)(gprm + O_FW0);
    const f2* f1x = (const f2*)(gprm + O_F1X);
    const f2* f1y = (const f2*)(gprm + O_F1Y);
    const f2* f1z = (const f2*)(gprm + O_F1Z);
    const f2* cwn = (const f2*)(gprm + O_CWN);
    const float Sc0 = gprm[O_SC], Sc1 = gprm[O_SC + 1];
    const int w = tid >> 6, lane = tid & 63;
    const int len = (w == 3) ? 7 : 6;
    const int l0 = (w < 3) ? (w * 384 + lane * 6) : (1152 + lane * 7);
    const float2* aLb = (const float2*)(gprm + ((w == 3) ? O_A7 : O_A6));
    float* orow = out + (size_t)b * SEQ;
    float4* r0q4 = (float4*)r0buf;
    const f2 z2 = {0.f, 0.f};

    f2 s0[PP];

    // ================= pass A: layer-0 local scan =================
#pragma unroll
    for (int p = 0; p < PP; p++) s0[p] = z2;
#pragma unroll 1
    for (int j = 0; j < len; j++) {
        int l = l0 + j;
        float xx = xl[l], sc = scl[l], sh = shl[l];
        float xs = xx * sc;
        f2 xs2 = {xs, xs}, sc2 = {sc, sc}, sh2 = {sh, sh};
#pragma unroll
        for (int p = 0; p < PP; p++) {
            f2 bu = pk_fma_s(g0c[p], sh2, z2);
            bu = pk_fma_s(g0b[p], sc2, bu);
            bu = pk_fma_s(g0a[p], xs2, bu);
            s0[p] = cfma_state(s0[p], lb0r[p], lb0i[p], bu);
        }
    }
    scan_carry256(s0, aLb, lane, w, aggA, aggS);

    // ================= pass B: layer-0 exact (stash r0) + layer-1 local =================
    f2 s1[PP];
#pragma unroll
    for (int p = 0; p < PP; p++) s1[p] = z2;
#pragma unroll 1
    for (int j = 0; j < len; j++) {
        int l = l0 + j;
        float xx = xl[l], sc = scl[l], sh = shl[l];
        float xs = xx * sc;
        f2 xs2 = {xs, xs}, sc2 = {sc, sc}, sh2 = {sh, sh}, xx2 = {xx, xx};
#pragma unroll
        for (int p = 0; p < PP; p++) {
            f2 bu = pk_fma_s(g0c[p], sh2, z2);
            bu = pk_fma_s(g0b[p], sc2, bu);
            bu = pk_fma_s(g0a[p], xs2, bu);
            s0[p] = cfma_state(s0[p], lb0r[p], lb0i[p], bu);
        }
        f2 r0p[6], t1[PP];
#pragma unroll
        for (int p = 0; p < PP; p++) t1[p] = z2;
#pragma unroll
        for (int h2 = 0; h2 < 6; h2++) {
            f2 acc = z2;
#pragma unroll
            for (int p = 0; p < PP; p++) {
                acc = pk_fma_s_blo(c0r[h2 * PP + p], s0[p], acc);
                acc = pk_fma_s_bhi(c0i[h2 * PP + p], s0[p], acc);
            }
            acc = pk_fma_s(fx0[h2], xs2, acc);
            acc = pk_fma_s(fy0[h2], sc2, acc);
            acc = pk_fma_s(fz0[h2], sh2, acc);
            acc.x = fmaxf(acc.x, 0.f); acc.y = fmaxf(acc.y, 0.f);
            r0p[h2] = acc;
#pragma unroll
            for (int p = 0; p < PP; p++) {
                t1[p] = pk_fma_s_blo(bb1[(2 * h2) * PP + p], acc, t1[p]);
                t1[p] = pk_fma_s_bhi(bb1[(2 * h2 + 1) * PP + p], acc, t1[p]);
            }
        }
        size_t base = r0base(b, j, tid);
        r0q4[base]       = make_float4(r0p[0].x, r0p[0].y, r0p[1].x, r0p[1].y);
        r0q4[base + 256] = make_float4(r0p[2].x, r0p[2].y, r0p[3].x, r0p[3].y);
        r0q4[base + 512] = make_float4(r0p[4].x, r0p[4].y, r0p[5].x, r0p[5].y);
#pragma unroll
        for (int p = 0; p < PP; p++) {
            f2 t = pk_fma_s(g1a[p], xx2, t1[p]);
            t = pk_add_s(g1b[p], t);
            s1[p] = cfma_state(s1[p], lb1r[p], lb1i[p], t);
        }
    }
    scan_carry256(s1, aLb + PP, lane, w, aggA, aggS);

    // ================= pass C: L1 exact (r0 loaded) + L2 local + out =================
    f2 s2[PP];
#pragma unroll
    for (int p = 0; p < PP; p++) s2[p] = z2;
    float4 nra, nrb, nrc;
    {
        size_t base = r0base(b, 0, tid);
        nra = r0q4[base]; nrb = r0q4[base + 256]; nrc = r0q4[base + 512];
    }
#pragma unroll 1
    for (int j = 0; j < len; j++) {
        int l = l0 + j;
        float4 ra = nra, rb = nrb, rc = nrc;
        if (j + 1 < len) {
            size_t base = r0base(b, j + 1, tid);
            nra = r0q4[base]; nrb = r0q4[base + 256]; nrc = r0q4[base + 512];
        }
        f2 r0p[6];
        r0p[0].x = ra.x; r0p[0].y = ra.y; r0p[1].x = ra.z; r0p[1].y = ra.w;
        r0p[2].x = rb.x; r0p[2].y = rb.y; r0p[3].x = rb.z; r0p[3].y = rb.w;
        r0p[4].x = rc.x; r0p[4].y = rc.y; r0p[5].x = rc.z; r0p[5].y = rc.w;
        float xx = xl[l];
        f2 xx2 = {xx, xx};
        f2 t1[PP];
#pragma unroll
        for (int p = 0; p < PP; p++) t1[p] = z2;
#pragma unroll
        for (int h2 = 0; h2 < 6; h2++) {
            f2 rp = r0p[h2];
#pragma unroll
            for (int p = 0; p < PP; p++) {
                t1[p] = pk_fma_s_blo(bb1[(2 * h2) * PP + p], rp, t1[p]);
                t1[p] = pk_fma_s_bhi(bb1[(2 * h2 + 1) * PP + p], rp, t1[p]);
            }
        }
#pragma unroll
        for (int p = 0; p < PP; p++) {
            f2 t = pk_fma_s(g1a[p], xx2, t1[p]);
            t = pk_add_s(g1b[p], t);
            s1[p] = cfma_state(s1[p], lb1r[p], lb1i[p], t);
        }
        // layer 2: rs = r0 + relu(y1) consumed from reg pairs
        f2 t2[PP], op = z2;
#pragma unroll
        for (int p = 0; p < PP; p++) t2[p] = z2;
#pragma unroll
        for (int h2 = 0; h2 < 6; h2++) {
            f2 acc = z2;
#pragma unroll
            for (int p = 0; p < PP; p++) {
                acc = pk_fma_s_blo(c1r[h2 * PP + p], s1[p], acc);
                acc = pk_fma_s_bhi(c1i[h2 * PP + p], s1[p], acc);
            }
            acc = pk_fma_s(f1y[h2], r0p[h2], acc);
            acc = pk_fma_s(fw0[h2], xx2, acc);
            acc = pk_add_s(f1x[h2], acc);
            acc.x = fmaxf(acc.x, 0.f); acc.y = fmaxf(acc.y, 0.f);
            f2 rsp = pk_add_vv(r0p[h2], acc);
            op = pk_fma_s(f1z[h2], rsp, op);
#pragma unroll
            for (int p = 0; p < PP; p++) {
                t2[p] = pk_fma_s_blo(bb2[(2 * h2) * PP + p], rsp, t2[p]);
                t2[p] = pk_fma_s_bhi(bb2[(2 * h2 + 1) * PP + p], rsp, t2[p]);
            }
        }
#pragma unroll
        for (int p = 0; p < PP; p++) {
            f2 t = pk_fma_s(g2a[p], xx2, t2[p]);
            t = pk_add_s(g2b[p], t);
            s2[p] = cfma_state(s2[p], lb2r[p], lb2i[p], t);
        }
        f2 a2 = z2;
#pragma unroll
        for (int p = 0; p < PP; p++) a2 = pk_fma_s(cwn[p], s2[p], a2);
        orow[l] = Sc0 + xx * Sc1 + op.x + op.y + a2.x + a2.y;   // partial
    }
    scan_carry256(s2, aLb + 2 * PP, lane, w, aggA, aggS);  // -> carry2

    // fixup: out[l] += Re(lam2^{j+1} * (2*cw) . carry2)
    float tr[PP], ti_[PP], mr[PP], mi_[PP];
#pragma unroll
    for (int p = 0; p < PP; p++) {
        float cwr = gprm[O_CWN + 2 * p], cwi = -gprm[O_CWN + 2 * p + 1];
        tr[p]  = cwr * s2[p].x - cwi * s2[p].y;
        ti_[p] = cwr * s2[p].y + cwi * s2[p].x;
        mr[p] = gprm[O_LB2R + 2 * p];
        mi_[p] = gprm[O_LB2I + 2 * p];
    }
#pragma unroll 1
    for (int j = 0; j < len; j++) {
        float corr = 0.f;
#pragma unroll
        for (int p = 0; p < PP; p++) corr += mr[p] * tr[p] - mi_[p] * ti_[p];
        orow[l0 + j] += corr;
#pragma unroll
        for (int p = 0; p < PP; p++) {
            float lr = gprm[O_LB2R + 2 * p], li = gprm[O_LB2I + 2 * p];
            float t = mr[p] * lr - mi_[p] * li;
            mi_[p] = mr[p] * li + mi_[p] * lr;
            mr[p] = t;
        }
    }
}

extern "C" void kernel_launch(void* const* d_in, const int* in_sizes, int n_in,
                              void* d_out, int out_size, void* d_ws, size_t ws_size,
                              hipStream_t stream) {
    const float* x     = (const float*)d_in[0];
    const float* l1w   = (const float*)d_in[1];
    const float* l1b   = (const float*)d_in[2];
    const float* l2w   = (const float*)d_in[3];
    const float* l2b   = (const float*)d_in[4];
    const float* gam   = (const float*)d_in[5];
    const float* bet   = (const float*)d_in[6];
    const float* lamr  = (const float*)d_in[7];
    const float* lami  = (const float*)d_in[8];
    const float* bre   = (const float*)d_in[9];
    const float* bim   = (const float*)d_in[10];
    const float* cre   = (const float*)d_in[11];
    const float* cim   = (const float*)d_in[12];
    const float* dv    = (const float*)d_in[13];
    const float* lstep = (const float*)d_in[14];
    float* out = (float*)d_out;

    float* wsf     = (float*)d_ws;
    float* w_scale = wsf;                  // 1600
    float* w_shift = wsf + SEQ;            // 1600
    float* pS      = wsf + 2 * SEQ;        // 16*1600
    float* pQ      = pS + 16 * SEQ;        // 16*1600
    float* gprm    = pQ + 16 * SEQ;        // PRMF (padded to 1280)
    float* r0buf   = gprm + 1280;          // 1024*7*3*256 float4 = 88 MB (round-8 proven)

    k_prep<<<dim3(1), 64, 0, stream>>>(l1w, l1b, l2w, l2b, lamr, lami,
                                       bre, bim, cre, cim, dv, lstep, gprm);
    k_stats1<<<dim3(7, 16), 256, 0, stream>>>(x, pS, pQ);
    k_stats2<<<dim3(7), 256, 0, stream>>>(pS, pQ, l1w, l1b, gam, bet, w_scale, w_shift);
    k_main<<<dim3(NB), 256, 0, stream>>>(x, gprm, w_scale, w_shift, r0buf, out);
}

// Round 18
// 249.293 us; speedup vs baseline: 1.0262x; 1.0262x over previous
//
#include <hip/hip_runtime.h>
#include <cmath>

#define SEQ 1600
#define NB  1024
#define H   12
#define PP  8

typedef float f2 __attribute__((ext_vector_type(2)));

// ---- param block offsets (floats) ----
#define O_G0A  0      // 8 x f2
#define O_G0B  16
#define O_G0C  32
#define O_G1A  48
#define O_G1B  64
#define O_G2A  80
#define O_G2B  96
#define O_LB0R 112    // 8 x f2 (lbr,lbr)
#define O_LB0I 128
#define O_LB1R 144
#define O_LB1I 160
#define O_LB2R 176
#define O_LB2I 192
#define O_C0R  208    // 48 x f2 (2*cre_h, 2*cre_h1), idx h2*8+p
#define O_C0I  304    // 48 x f2 (-2*cim_h, -2*cim_h1)
#define O_C1R  400
#define O_C1I  496
#define O_BB1  592    // 96 x f2 (re,im), idx h*8+p
#define O_BB2  784
#define O_FX0  976    // 6 x f2 h-pairs
#define O_FY0  988
#define O_FZ0  1000
#define O_FW0  1012
#define O_F1X  1024
#define O_F1Y  1036
#define O_F1Z  1048
#define O_CWN  1060   // 8 x f2 (2*re, -2*im)
#define O_A6   1076   // 24 x float2
#define O_A7   1124
#define O_SC   1172   // 2 floats
#define PRMF   1174

// ---- packed fp32 helpers ----
__device__ __forceinline__ f2 pk_fma_s(f2 a_s, f2 b, f2 c) {
    double d;
    asm("v_pk_fma_f32 %0, %1, %2, %3"
        : "=v"(d)
        : "s"(__builtin_bit_cast(double, a_s)),
          "v"(__builtin_bit_cast(double, b)),
          "v"(__builtin_bit_cast(double, c)));
    return __builtin_bit_cast(f2, d);
}
__device__ __forceinline__ f2 pk_fma_vv(f2 a, f2 b, f2 c) {
    double d;
    asm("v_pk_fma_f32 %0, %1, %2, %3"
        : "=v"(d)
        : "v"(__builtin_bit_cast(double, a)),
          "v"(__builtin_bit_cast(double, b)),
          "v"(__builtin_bit_cast(double, c)));
    return __builtin_bit_cast(f2, d);
}
__device__ __forceinline__ f2 pk_fma_s_blo(f2 a_s, f2 b, f2 c) {
    double d;
    asm("v_pk_fma_f32 %0, %1, %2, %3 op_sel:[0,0,0] op_sel_hi:[1,0,1]"
        : "=v"(d)
        : "s"(__builtin_bit_cast(double, a_s)),
          "v"(__builtin_bit_cast(double, b)),
          "v"(__builtin_bit_cast(double, c)));
    return __builtin_bit_cast(f2, d);
}
__device__ __forceinline__ f2 pk_fma_s_bhi(f2 a_s, f2 b, f2 c) {
    double d;
    asm("v_pk_fma_f32 %0, %1, %2, %3 op_sel:[0,1,0] op_sel_hi:[1,1,1]"
        : "=v"(d)
        : "s"(__builtin_bit_cast(double, a_s)),
          "v"(__builtin_bit_cast(double, b)),
          "v"(__builtin_bit_cast(double, c)));
    return __builtin_bit_cast(f2, d);
}
__device__ __forceinline__ f2 pk_add_s(f2 a_s, f2 b) {
    double d;
    asm("v_pk_add_f32 %0, %1, %2"
        : "=v"(d)
        : "s"(__builtin_bit_cast(double, a_s)),
          "v"(__builtin_bit_cast(double, b)));
    return __builtin_bit_cast(f2, d);
}
__device__ __forceinline__ f2 pk_add_vv(f2 a, f2 b) {
    double d;
    asm("v_pk_add_f32 %0, %1, %2"
        : "=v"(d)
        : "v"(__builtin_bit_cast(double, a)),
          "v"(__builtin_bit_cast(double, b)));
    return __builtin_bit_cast(f2, d);
}
// s' = (lbr + i*lbi) * s + bu
__device__ __forceinline__ f2 cfma_state(f2 s, f2 lbr2_s, f2 lbi2_s, f2 bu) {
    double t, d;
    asm("v_pk_fma_f32 %0, %1, %2, %3 op_sel:[1,0,0] op_sel_hi:[0,1,1] neg_lo:[1,0,0]"
        : "=v"(t)
        : "v"(__builtin_bit_cast(double, s)),
          "s"(__builtin_bit_cast(double, lbi2_s)),
          "v"(__builtin_bit_cast(double, bu)));
    asm("v_pk_fma_f32 %0, %1, %2, %3"
        : "=v"(d)
        : "v"(__builtin_bit_cast(double, s)),
          "s"(__builtin_bit_cast(double, lbr2_s)),
          "v"(t));
    return __builtin_bit_cast(f2, d);
}

// ---------------- BN stats ----------------
__global__ __launch_bounds__(256) void k_stats1(const float* __restrict__ x,
                                                float* __restrict__ pS,
                                                float* __restrict__ pQ) {
    int l = blockIdx.x * 256 + threadIdx.x;
    if (l >= SEQ) return;
    int b0 = blockIdx.y * 64;
    float s = 0.f, q = 0.f;
    for (int b = 0; b < 64; ++b) {
        float v = x[(size_t)(b0 + b) * SEQ + l];
        s += v; q += v * v;
    }
    pS[blockIdx.y * SEQ + l] = s;
    pQ[blockIdx.y * SEQ + l] = q;
}

// ---------------- stats2 (blocks 0-6) + prep (block 7) merged ----------------
__global__ __launch_bounds__(256)
void k_stats2prep(const float* __restrict__ pS, const float* __restrict__ pQ,
                  const float* __restrict__ w1, const float* __restrict__ b1,
                  const float* __restrict__ gam, const float* __restrict__ bet,
                  float* __restrict__ scale, float* __restrict__ shift,
                  const float* __restrict__ l2w, const float* __restrict__ l2b,
                  const float* __restrict__ lamr, const float* __restrict__ lami,
                  const float* __restrict__ bre, const float* __restrict__ bim,
                  const float* __restrict__ cre, const float* __restrict__ cim,
                  const float* __restrict__ dv,  const float* __restrict__ lstep,
                  float* __restrict__ gprm) {
    const int t = threadIdx.x;
    if (blockIdx.x < 7) {
        int l = blockIdx.x * 256 + t;
        if (l >= SEQ) return;
        float wm = 0, wq = 0, wb = 0, bm = 0, bq = 0;
        for (int h = 0; h < H; h++) {
            float w = w1[h], b = b1[h];
            wm += w; wq += w * w; wb += w * b; bm += b; bq += b * b;
        }
        const float inv = 1.f / 12.f;
        wm *= inv; wq *= inv; wb *= inv; bm *= inv; bq *= inv;
        float s = 0, q = 0;
        for (int k = 0; k < 16; k++) { s += pS[k * SEQ + l]; q += pQ[k * SEQ + l]; }
        float ex = s * (1.f / NB), exx = q * (1.f / NB);
        float mean = ex * wm + bm;
        float e2   = exx * wq + 2.f * ex * wb + bq;
        float var  = e2 - mean * mean;
        float sc   = gam[l] * rsqrtf(var + 1e-5f);
        scale[l] = sc;
        shift[l] = bet[l] - mean * sc;
        return;
    }
    // ---- block 7: derived parameters ----
    if (t < 48) {   // C matrices as h-pair tables, pre-scaled by 2
        int h2 = t >> 3, p = t & 7, h = 2 * h2;
        gprm[O_C0R + 2 * t]     = 2.f * cre[h * PP + p];
        gprm[O_C0R + 2 * t + 1] = 2.f * cre[(h + 1) * PP + p];
        gprm[O_C0I + 2 * t]     = -2.f * cim[h * PP + p];
        gprm[O_C0I + 2 * t + 1] = -2.f * cim[(h + 1) * PP + p];
        gprm[O_C1R + 2 * t]     = 2.f * cre[96 + h * PP + p];
        gprm[O_C1R + 2 * t + 1] = 2.f * cre[96 + (h + 1) * PP + p];
        gprm[O_C1I + 2 * t]     = -2.f * cim[96 + h * PP + p];
        gprm[O_C1I + 2 * t + 1] = -2.f * cim[96 + (h + 1) * PP + p];
    }
    if (t < 6) {    // finish tables as h-pairs
        int h = 2 * t;
        gprm[O_FX0 + 2 * t] = w1[h] * dv[h];          gprm[O_FX0 + 2 * t + 1] = w1[h + 1] * dv[h + 1];
        gprm[O_FY0 + 2 * t] = b1[h] * dv[h];          gprm[O_FY0 + 2 * t + 1] = b1[h + 1] * dv[h + 1];
        gprm[O_FZ0 + 2 * t] = dv[h];                  gprm[O_FZ0 + 2 * t + 1] = dv[h + 1];
        gprm[O_FW0 + 2 * t] = w1[h] * dv[H + h];      gprm[O_FW0 + 2 * t + 1] = w1[h + 1] * dv[H + h + 1];
        gprm[O_F1X + 2 * t] = b1[h] * dv[H + h];      gprm[O_F1X + 2 * t + 1] = b1[h + 1] * dv[H + h + 1];
        gprm[O_F1Y + 2 * t] = dv[H + h];              gprm[O_F1Y + 2 * t + 1] = dv[H + h + 1];
        gprm[O_F1Z + 2 * t] = l2w[h] * dv[2 * H + h]; gprm[O_F1Z + 2 * t + 1] = l2w[h + 1] * dv[2 * H + h + 1];
    }
    if (t == 0) {
        float s0 = l2b[0], s1 = 0.f;
        for (int h = 0; h < H; h++) {
            float dw = l2w[h] * dv[2 * H + h];
            s0 += b1[h] * dw; s1 += w1[h] * dw;
        }
        gprm[O_SC + 0] = s0; gprm[O_SC + 1] = s1;
    }
    if (t < 24) {
        int L = t >> 3, p = t & 7;
        float stp = expf(lstep[L * PP + p]);
        float lr = lamr[L * PP + p], li = lami[L * PP + p];
        float er = expf(lr * stp);
        float lbr = er * cosf(li * stp), lbi = er * sinf(li * stp);   // lam_bar
        float p2r = lbr * lbr - lbi * lbi, p2i = 2.f * lbr * lbi;
        float p4r = p2r * p2r - p2i * p2i, p4i = 2.f * p2r * p2i;
        float p6r = p4r * p2r - p4i * p2i, p6i = p4r * p2i + p4i * p2r;
        float p7r = p6r * lbr - p6i * lbi, p7i = p6r * lbi + p6i * lbr;
        gprm[O_A6 + 2 * (L * PP + p) + 0] = p6r;
        gprm[O_A6 + 2 * (L * PP + p) + 1] = p6i;
        gprm[O_A7 + 2 * (L * PP + p) + 0] = p7r;
        gprm[O_A7 + 2 * (L * PP + p) + 1] = p7i;
        float den = lr * lr + li * li;
        float fr = ((lbr - 1.f) * lr + lbi * li) / den;
        float fi = (lbi * lr - (lbr - 1.f) * li) / den;
        float sAr = 0, sAi = 0, sBr = 0, sBi = 0, sCr = 0, sCi = 0;
        for (int h = 0; h < H; h++) {
            float brr = bre[L * 96 + p * H + h], bii = bim[L * 96 + p * H + h];
            float vr = fr * brr - fi * bii, vi = fr * bii + fi * brr;  // b_bar[p,h]
            float w = w1[h], bb = b1[h];
            sAr += w * vr; sAi += w * vi; sBr += bb * vr; sBi += bb * vi; sCr += vr; sCi += vi;
            int fidx = 2 * (h * PP + p);
            if (L == 1)      { gprm[O_BB1 + fidx] = vr; gprm[O_BB1 + fidx + 1] = vi; }
            else if (L == 2) { gprm[O_BB2 + fidx] = vr; gprm[O_BB2 + fidx + 1] = vi; }
        }
        if (L == 0) {
            gprm[O_G0A + 2 * p] = sAr; gprm[O_G0A + 2 * p + 1] = sAi;
            gprm[O_G0B + 2 * p] = sBr; gprm[O_G0B + 2 * p + 1] = sBi;
            gprm[O_G0C + 2 * p] = sCr; gprm[O_G0C + 2 * p + 1] = sCi;
            gprm[O_LB0R + 2 * p] = lbr; gprm[O_LB0R + 2 * p + 1] = lbr;
            gprm[O_LB0I + 2 * p] = lbi; gprm[O_LB0I + 2 * p + 1] = lbi;
        } else if (L == 1) {
            gprm[O_G1A + 2 * p] = sAr; gprm[O_G1A + 2 * p + 1] = sAi;
            gprm[O_G1B + 2 * p] = sBr; gprm[O_G1B + 2 * p + 1] = sBi;
            gprm[O_LB1R + 2 * p] = lbr; gprm[O_LB1R + 2 * p + 1] = lbr;
            gprm[O_LB1I + 2 * p] = lbi; gprm[O_LB1I + 2 * p + 1] = lbi;
        } else {
            gprm[O_G2A + 2 * p] = sAr; gprm[O_G2A + 2 * p + 1] = sAi;
            gprm[O_G2B + 2 * p] = sBr; gprm[O_G2B + 2 * p + 1] = sBi;
            gprm[O_LB2R + 2 * p] = lbr; gprm[O_LB2R + 2 * p + 1] = lbr;
            gprm[O_LB2I + 2 * p] = lbi; gprm[O_LB2I + 2 * p + 1] = lbi;
            float swr = 0, swi = 0;
            for (int hh = 0; hh < H; hh++) {
                float wv = l2w[hh];
                swr += wv * cre[192 + hh * PP + p];
                swi += wv * cim[192 + hh * PP + p];
            }
            gprm[O_CWN + 2 * p + 0] = 2.f * swr; gprm[O_CWN + 2 * p + 1] = -2.f * swi;
        }
    }
}

// ---- hierarchical carry scan across 256 threads (f2 states) ----
__device__ __forceinline__ void scan_carry256(f2* S, const float2* a_init,
                                              int lane, int w,
                                              float2 (*aggA)[PP], float2 (*aggS)[PP]) {
    f2 A[PP];
#pragma unroll
    for (int p = 0; p < PP; p++) { A[p].x = a_init[p].x; A[p].y = a_init[p].y; }
#pragma unroll
    for (int d = 1; d < 64; d <<= 1) {
#pragma unroll
        for (int p = 0; p < PP; p++) {
            float fSr = __shfl_up(S[p].x, (unsigned)d, 64);
            float fSi = __shfl_up(S[p].y, (unsigned)d, 64);
            float fAr = __shfl_up(A[p].x, (unsigned)d, 64);
            float fAi = __shfl_up(A[p].y, (unsigned)d, 64);
            if (lane >= d) {
                float nsr = A[p].x * fSr - A[p].y * fSi + S[p].x;
                float nsi = A[p].x * fSi + A[p].y * fSr + S[p].y;
                float nar = fAr * A[p].x - fAi * A[p].y;
                float nai = fAr * A[p].y + fAi * A[p].x;
                S[p].x = nsr; S[p].y = nsi; A[p].x = nar; A[p].y = nai;
            }
        }
    }
    __syncthreads();
    if (lane == 63) {
#pragma unroll
        for (int p = 0; p < PP; p++) {
            aggA[w][p] = make_float2(A[p].x, A[p].y);
            aggS[w][p] = make_float2(S[p].x, S[p].y);
        }
    }
    __syncthreads();
    float eSr[PP], eSi[PP], eAr[PP], eAi[PP];
#pragma unroll
    for (int p = 0; p < PP; p++) {
        float sr = __shfl_up(S[p].x, 1u, 64);
        float si = __shfl_up(S[p].y, 1u, 64);
        float ar = __shfl_up(A[p].x, 1u, 64);
        float ai = __shfl_up(A[p].y, 1u, 64);
        eSr[p] = (lane > 0) ? sr : 0.f;
        eSi[p] = (lane > 0) ? si : 0.f;
        eAr[p] = (lane > 0) ? ar : 1.f;
        eAi[p] = (lane > 0) ? ai : 0.f;
    }
    float Pr[PP], Pi[PP];
#pragma unroll
    for (int p = 0; p < PP; p++) { Pr[p] = 0.f; Pi[p] = 0.f; }
    for (int w2 = 0; w2 < w; w2++) {
#pragma unroll
        for (int p = 0; p < PP; p++) {
            float2 a = aggA[w2][p];
            float2 s = aggS[w2][p];
            float nr = a.x * Pr[p] - a.y * Pi[p] + s.x;
            float ni = a.x * Pi[p] + a.y * Pr[p] + s.y;
            Pr[p] = nr; Pi[p] = ni;
        }
    }
#pragma unroll
    for (int p = 0; p < PP; p++) {
        S[p].x = eAr[p] * Pr[p] - eAi[p] * Pi[p] + eSr[p];
        S[p].y = eAr[p] * Pi[p] + eAi[p] * Pr[p] + eSi[p];
    }
}

// ---------------- fully fused: 3 layers, h-pair packed fp32 ----------------
__global__ __launch_bounds__(256)
void k_main(const float* __restrict__ x,
            const float* __restrict__ gprm,
            const float* __restrict__ g_scale, const float* __restrict__ g_shift,
            float* __restrict__ out) {
    __shared__ float xl[SEQ], scl[SEQ], shl[SEQ];
    __shared__ float2 aggA[4][PP], aggS[4][PP];
    const int tid = threadIdx.x, b = blockIdx.x;
    for (int i = tid; i < SEQ; i += 256) {
        xl[i] = x[(size_t)b * SEQ + i];
        scl[i] = g_scale[i];
        shl[i] = g_shift[i];
    }
    __syncthreads();
    const f2* g0a = (const f2*)(gprm + O_G0A);
    const f2* g0b = (const f2*)(gprm + O_G0B);
    const f2* g0c = (const f2*)(gprm + O_G0C);
    const f2* g1a = (const f2*)(gprm + O_G1A);
    const f2* g1b = (const f2*)(gprm + O_G1B);
    const f2* g2a = (const f2*)(gprm + O_G2A);
    const f2* g2b = (const f2*)(gprm + O_G2B);
    const f2* lb0r = (const f2*)(gprm + O_LB0R);
    const f2* lb0i = (const f2*)(gprm + O_LB0I);
    const f2* lb1r = (const f2*)(gprm + O_LB1R);
    const f2* lb1i = (const f2*)(gprm + O_LB1I);
    const f2* lb2r = (const f2*)(gprm + O_LB2R);
    const f2* lb2i = (const f2*)(gprm + O_LB2I);
    const f2* c0r = (const f2*)(gprm + O_C0R);
    const f2* c0i = (const f2*)(gprm + O_C0I);
    const f2* c1r = (const f2*)(gprm + O_C1R);
    const f2* c1i = (const f2*)(gprm + O_C1I);
    const f2* bb1 = (const f2*)(gprm + O_BB1);
    const f2* bb2 = (const f2*)(gprm + O_BB2);
    const f2* fx0 = (const f2*)(gprm + O_FX0);
    const f2* fy0 = (const f2*)(gprm + O_FY0);
    const f2* fz0 = (const f2*)(gprm + O_FZ0);
    const f2* fw0 = (const f2*)(gprm + O_FW0);
    const f2* f1x = (const f2*)(gprm + O_F1X);
    const f2* f1y = (const f2*)(gprm + O_F1Y);
    const f2* f1z = (const f2*)(gprm + O_F1Z);
    const f2* cwn = (const f2*)(gprm + O_CWN);
    const float Sc0 = gprm[O_SC], Sc1 = gprm[O_SC + 1];
    const int w = tid >> 6, lane = tid & 63;
    const int len = (w == 3) ? 7 : 6;
    const int l0 = (w < 3) ? (w * 384 + lane * 6) : (1152 + lane * 7);
    const float2* aLb = (const float2*)(gprm + ((w == 3) ? O_A7 : O_A6));
    float* orow = out + (size_t)b * SEQ;
    const f2 z2 = {0.f, 0.f};

    f2 s0[PP], car0[PP];

    // ================= pass A: layer-0 local scan =================
#pragma unroll
    for (int p = 0; p < PP; p++) s0[p] = z2;
#pragma unroll 1
    for (int j = 0; j < len; j++) {
        int l = l0 + j;
        float xx = xl[l], sc = scl[l], sh = shl[l];
        float xs = xx * sc;
        f2 xs2 = {xs, xs}, sc2 = {sc, sc}, sh2 = {sh, sh};
#pragma unroll
        for (int p = 0; p < PP; p++) {
            f2 bu = pk_fma_s(g0c[p], sh2, z2);
            bu = pk_fma_s(g0b[p], sc2, bu);
            bu = pk_fma_s(g0a[p], xs2, bu);
            s0[p] = cfma_state(s0[p], lb0r[p], lb0i[p], bu);
        }
    }
    scan_carry256(s0, aLb, lane, w, aggA, aggS);
#pragma unroll
    for (int p = 0; p < PP; p++) car0[p] = s0[p];

    // ================= pass B: layer-0 exact + layer-1 local =================
    f2 s1[PP];
#pragma unroll
    for (int p = 0; p < PP; p++) s1[p] = z2;
#pragma unroll 1
    for (int j = 0; j < len; j++) {
        int l = l0 + j;
        float xx = xl[l], sc = scl[l], sh = shl[l];
        float xs = xx * sc;
        f2 xs2 = {xs, xs}, sc2 = {sc, sc}, sh2 = {sh, sh}, xx2 = {xx, xx};
#pragma unroll
        for (int p = 0; p < PP; p++) {
            f2 bu = pk_fma_s(g0c[p], sh2, z2);
            bu = pk_fma_s(g0b[p], sc2, bu);
            bu = pk_fma_s(g0a[p], xs2, bu);
            s0[p] = cfma_state(s0[p], lb0r[p], lb0i[p], bu);
        }
        f2 r0p[6], t1[PP];
#pragma unroll
        for (int p = 0; p < PP; p++) t1[p] = z2;
#pragma unroll
        for (int h2 = 0; h2 < 6; h2++) {
            f2 acc = z2;
#pragma unroll
            for (int p = 0; p < PP; p++) {
                acc = pk_fma_s_blo(c0r[h2 * PP + p], s0[p], acc);
                acc = pk_fma_s_bhi(c0i[h2 * PP + p], s0[p], acc);
            }
            acc = pk_fma_s(fx0[h2], xs2, acc);
            acc = pk_fma_s(fy0[h2], sc2, acc);
            acc = pk_fma_s(fz0[h2], sh2, acc);
            acc.x = fmaxf(acc.x, 0.f); acc.y = fmaxf(acc.y, 0.f);
            r0p[h2] = acc;
#pragma unroll
            for (int p = 0; p < PP; p++) {
                t1[p] = pk_fma_s_blo(bb1[(2 * h2) * PP + p], acc, t1[p]);
                t1[p] = pk_fma_s_bhi(bb1[(2 * h2 + 1) * PP + p], acc, t1[p]);
            }
        }
#pragma unroll
        for (int p = 0; p < PP; p++) {
            f2 t = pk_fma_s(g1a[p], xx2, t1[p]);
            t = pk_add_s(g1b[p], t);
            s1[p] = cfma_state(s1[p], lb1r[p], lb1i[p], t);
        }
    }
    scan_carry256(s1, aLb + PP, lane, w, aggA, aggS);

    // ================= pass C: L0 exact + L1 exact + L2 local + out =================
    f2 s2[PP];
#pragma unroll
    for (int p = 0; p < PP; p++) { s0[p] = car0[p]; s2[p] = z2; }
#pragma unroll 1
    for (int j = 0; j < len; j++) {
        int l = l0 + j;
        float xx = xl[l], sc = scl[l], sh = shl[l];
        float xs = xx * sc;
        f2 xs2 = {xs, xs}, sc2 = {sc, sc}, sh2 = {sh, sh}, xx2 = {xx, xx};
#pragma unroll
        for (int p = 0; p < PP; p++) {
            f2 bu = pk_fma_s(g0c[p], sh2, z2);
            bu = pk_fma_s(g0b[p], sc2, bu);
            bu = pk_fma_s(g0a[p], xs2, bu);
            s0[p] = cfma_state(s0[p], lb0r[p], lb0i[p], bu);
        }
        f2 r0p[6], t1[PP];
#pragma unroll
        for (int p = 0; p < PP; p++) t1[p] = z2;
#pragma unroll
        for (int h2 = 0; h2 < 6; h2++) {
            f2 acc = z2;
#pragma unroll
            for (int p = 0; p < PP; p++) {
                acc = pk_fma_s_blo(c0r[h2 * PP + p], s0[p], acc);
                acc = pk_fma_s_bhi(c0i[h2 * PP + p], s0[p], acc);
            }
            acc = pk_fma_s(fx0[h2], xs2, acc);
            acc = pk_fma_s(fy0[h2], sc2, acc);
            acc = pk_fma_s(fz0[h2], sh2, acc);
            acc.x = fmaxf(acc.x, 0.f); acc.y = fmaxf(acc.y, 0.f);
            r0p[h2] = acc;
#pragma unroll
            for (int p = 0; p < PP; p++) {
                t1[p] = pk_fma_s_blo(bb1[(2 * h2) * PP + p], acc, t1[p]);
                t1[p] = pk_fma_s_bhi(bb1[(2 * h2 + 1) * PP + p], acc, t1[p]);
            }
        }
#pragma unroll
        for (int p = 0; p < PP; p++) {
            f2 t = pk_fma_s(g1a[p], xx2, t1[p]);
            t = pk_add_s(g1b[p], t);
            s1[p] = cfma_state(s1[p], lb1r[p], lb1i[p], t);
        }
        // layer 2: rs = r0 + relu(y1) consumed from reg pairs
        f2 t2[PP], op = z2;
#pragma unroll
        for (int p = 0; p < PP; p++) t2[p] = z2;
#pragma unroll
        for (int h2 = 0; h2 < 6; h2++) {
            f2 acc = z2;
#pragma unroll
            for (int p = 0; p < PP; p++) {
                acc = pk_fma_s_blo(c1r[h2 * PP + p], s1[p], acc);
                acc = pk_fma_s_bhi(c1i[h2 * PP + p], s1[p], acc);
            }
            acc = pk_fma_s(f1y[h2], r0p[h2], acc);
            acc = pk_fma_s(fw0[h2], xx2, acc);
            acc = pk_add_s(f1x[h2], acc);
            acc.x = fmaxf(acc.x, 0.f); acc.y = fmaxf(acc.y, 0.f);
            f2 rsp = pk_add_vv(r0p[h2], acc);
            op = pk_fma_s(f1z[h2], rsp, op);
#pragma unroll
            for (int p = 0; p < PP; p++) {
                t2[p] = pk_fma_s_blo(bb2[(2 * h2) * PP + p], rsp, t2[p]);
                t2[p] = pk_fma_s_bhi(bb2[(2 * h2 + 1) * PP + p], rsp, t2[p]);
            }
        }
#pragma unroll
        for (int p = 0; p < PP; p++) {
            f2 t = pk_fma_s(g2a[p], xx2, t2[p]);
            t = pk_add_s(g2b[p], t);
            s2[p] = cfma_state(s2[p], lb2r[p], lb2i[p], t);
        }
        f2 a2 = z2;
#pragma unroll
        for (int p = 0; p < PP; p++) a2 = pk_fma_s(cwn[p], s2[p], a2);
        orow[l] = Sc0 + xx * Sc1 + op.x + op.y + a2.x + a2.y;   // partial
    }
    scan_carry256(s2, aLb + 2 * PP, lane, w, aggA, aggS);  // -> carry2

    // fixup: out[l] += Re(lam2^{j+1} * (2*cw) . carry2)  — pk-packed
    f2 Tn[PP], m[PP];
#pragma unroll
    for (int p = 0; p < PP; p++) {
        float cwr = gprm[O_CWN + 2 * p], cwi = -gprm[O_CWN + 2 * p + 1];  // 2*swr, 2*swi
        float trr = cwr * s2[p].x - cwi * s2[p].y;
        float tii = cwr * s2[p].y + cwi * s2[p].x;
        Tn[p].x = trr; Tn[p].y = -tii;       // (Tr, -Ti): Re(m.T) = m . Tn
        m[p].x = gprm[O_LB2R + 2 * p];
        m[p].y = gprm[O_LB2I + 2 * p];       // lam2
    }
#pragma unroll 1
    for (int j = 0; j < len; j++) {
        f2 cacc = z2;
#pragma unroll
        for (int p = 0; p < PP; p++) cacc = pk_fma_vv(m[p], Tn[p], cacc);
        orow[l0 + j] += cacc.x + cacc.y;
#pragma unroll
        for (int p = 0; p < PP; p++)
            m[p] = cfma_state(m[p], lb2r[p], lb2i[p], z2);   // m *= lam2
    }
}

extern "C" void kernel_launch(void* const* d_in, const int* in_sizes, int n_in,
                              void* d_out, int out_size, void* d_ws, size_t ws_size,
                              hipStream_t stream) {
    const float* x     = (const float*)d_in[0];
    const float* l1w   = (const float*)d_in[1];
    const float* l1b   = (const float*)d_in[2];
    const float* l2w   = (const float*)d_in[3];
    const float* l2b   = (const float*)d_in[4];
    const float* gam   = (const float*)d_in[5];
    const float* bet   = (const float*)d_in[6];
    const float* lamr  = (const float*)d_in[7];
    const float* lami  = (const float*)d_in[8];
    const float* bre   = (const float*)d_in[9];
    const float* bim   = (const float*)d_in[10];
    const float* cre   = (const float*)d_in[11];
    const float* cim   = (const float*)d_in[12];
    const float* dv    = (const float*)d_in[13];
    const float* lstep = (const float*)d_in[14];
    float* out = (float*)d_out;

    float* wsf     = (float*)d_ws;
    float* w_scale = wsf;                  // 1600
    float* w_shift = wsf + SEQ;            // 1600
    float* pS      = wsf + 2 * SEQ;        // 16*1600
    float* pQ      = pS + 16 * SEQ;        // 16*1600
    float* gprm    = pQ + 16 * SEQ;        // PRMF (padded to 1280)

    k_stats1<<<dim3(7, 16), 256, 0, stream>>>(x, pS, pQ);
    k_stats2prep<<<dim3(8), 256, 0, stream>>>(pS, pQ, l1w, l1b, gam, bet,
                                              w_scale, w_shift,
                                              l2w, l2b, lamr, lami,
                                              bre, bim, cre, cim, dv, lstep, gprm);
    k_main<<<dim3(NB), 256, 0, stream>>>(x, gprm, w_scale, w_shift, out);
}

// Round 19
// 197.600 us; speedup vs baseline: 1.2946x; 1.2616x over previous
//
#include <hip/hip_runtime.h>
#include <cmath>

#define SEQ 1600
#define NB  1024
#define H   12
#define PP  8

typedef float f2 __attribute__((ext_vector_type(2)));

// ---- param block offsets (floats) ----
#define O_G0A  0      // 8 x f2
#define O_G0B  16
#define O_G0C  32
#define O_G1A  48
#define O_G1B  64
#define O_G2A  80
#define O_G2B  96
#define O_LB0R 112    // 8 x f2 (lbr,lbr)
#define O_LB0I 128
#define O_LB1R 144
#define O_LB1I 160
#define O_LB2R 176
#define O_LB2I 192
#define O_C0R  208    // 48 x f2 (2*cre_h, 2*cre_h1), idx h2*8+p
#define O_C0I  304    // 48 x f2 (-2*cim_h, -2*cim_h1)
#define O_C1R  400
#define O_C1I  496
#define O_BB1  592    // 96 x f2 (re,im), idx h*8+p
#define O_BB2  784
#define O_FX0  976    // 6 x f2 h-pairs
#define O_FY0  988
#define O_FZ0  1000
#define O_FW0  1012
#define O_F1X  1024
#define O_F1Y  1036
#define O_F1Z  1048
#define O_CWN  1060   // 8 x f2 (2*re, -2*im)
#define O_A6   1076   // 24 x float2
#define O_A7   1124
#define O_SC   1172   // 2 floats
#define PRMF   1174

// ---- packed fp32 helpers ----
__device__ __forceinline__ f2 pk_fma_s(f2 a_s, f2 b, f2 c) {
    double d;
    asm("v_pk_fma_f32 %0, %1, %2, %3"
        : "=v"(d)
        : "s"(__builtin_bit_cast(double, a_s)),
          "v"(__builtin_bit_cast(double, b)),
          "v"(__builtin_bit_cast(double, c)));
    return __builtin_bit_cast(f2, d);
}
__device__ __forceinline__ f2 pk_fma_vv(f2 a, f2 b, f2 c) {
    double d;
    asm("v_pk_fma_f32 %0, %1, %2, %3"
        : "=v"(d)
        : "v"(__builtin_bit_cast(double, a)),
          "v"(__builtin_bit_cast(double, b)),
          "v"(__builtin_bit_cast(double, c)));
    return __builtin_bit_cast(f2, d);
}
__device__ __forceinline__ f2 pk_fma_s_blo(f2 a_s, f2 b, f2 c) {
    double d;
    asm("v_pk_fma_f32 %0, %1, %2, %3 op_sel:[0,0,0] op_sel_hi:[1,0,1]"
        : "=v"(d)
        : "s"(__builtin_bit_cast(double, a_s)),
          "v"(__builtin_bit_cast(double, b)),
          "v"(__builtin_bit_cast(double, c)));
    return __builtin_bit_cast(f2, d);
}
__device__ __forceinline__ f2 pk_fma_s_bhi(f2 a_s, f2 b, f2 c) {
    double d;
    asm("v_pk_fma_f32 %0, %1, %2, %3 op_sel:[0,1,0] op_sel_hi:[1,1,1]"
        : "=v"(d)
        : "s"(__builtin_bit_cast(double, a_s)),
          "v"(__builtin_bit_cast(double, b)),
          "v"(__builtin_bit_cast(double, c)));
    return __builtin_bit_cast(f2, d);
}
__device__ __forceinline__ f2 pk_add_s(f2 a_s, f2 b) {
    double d;
    asm("v_pk_add_f32 %0, %1, %2"
        : "=v"(d)
        : "s"(__builtin_bit_cast(double, a_s)),
          "v"(__builtin_bit_cast(double, b)));
    return __builtin_bit_cast(f2, d);
}
__device__ __forceinline__ f2 pk_add_vv(f2 a, f2 b) {
    double d;
    asm("v_pk_add_f32 %0, %1, %2"
        : "=v"(d)
        : "v"(__builtin_bit_cast(double, a)),
          "v"(__builtin_bit_cast(double, b)));
    return __builtin_bit_cast(f2, d);
}
// s' = (lbr + i*lbi) * s + bu  (lbr/lbi duplicated pairs, scalar operand)
__device__ __forceinline__ f2 cfma_state(f2 s, f2 lbr2_s, f2 lbi2_s, f2 bu) {
    double t, d;
    asm("v_pk_fma_f32 %0, %1, %2, %3 op_sel:[1,0,0] op_sel_hi:[0,1,1] neg_lo:[1,0,0]"
        : "=v"(t)
        : "v"(__builtin_bit_cast(double, s)),
          "s"(__builtin_bit_cast(double, lbi2_s)),
          "v"(__builtin_bit_cast(double, bu)));
    asm("v_pk_fma_f32 %0, %1, %2, %3"
        : "=v"(d)
        : "v"(__builtin_bit_cast(double, s)),
          "s"(__builtin_bit_cast(double, lbr2_s)),
          "v"(t));
    return __builtin_bit_cast(f2, d);
}
// d = A (x) B + C, all-VGPR complex multiply-add: A,B complex (re,im)
__device__ __forceinline__ f2 cmulv(f2 A, f2 B, f2 C) {
    double t, d;
    // t.lo = -B.im*A.im + C.re ; t.hi = B.re*A.im + C.im
    asm("v_pk_fma_f32 %0, %1, %2, %3 op_sel:[1,1,0] op_sel_hi:[0,1,1] neg_lo:[1,0,0]"
        : "=v"(t)
        : "v"(__builtin_bit_cast(double, B)),
          "v"(__builtin_bit_cast(double, A)),
          "v"(__builtin_bit_cast(double, C)));
    // d.lo = B.re*A.re + t.lo ; d.hi = B.im*A.re + t.hi
    asm("v_pk_fma_f32 %0, %1, %2, %3 op_sel:[0,0,0] op_sel_hi:[1,0,1]"
        : "=v"(d)
        : "v"(__builtin_bit_cast(double, B)),
          "v"(__builtin_bit_cast(double, A)),
          "v"(t));
    return __builtin_bit_cast(f2, d);
}

// ---------------- BN stats ----------------
__global__ __launch_bounds__(256) void k_stats1(const float* __restrict__ x,
                                                float* __restrict__ pS,
                                                float* __restrict__ pQ) {
    int l = blockIdx.x * 256 + threadIdx.x;
    if (l >= SEQ) return;
    int b0 = blockIdx.y * 64;
    float s = 0.f, q = 0.f;
    for (int b = 0; b < 64; ++b) {
        float v = x[(size_t)(b0 + b) * SEQ + l];
        s += v; q += v * v;
    }
    pS[blockIdx.y * SEQ + l] = s;
    pQ[blockIdx.y * SEQ + l] = q;
}

// ---------------- stats2 (blocks 0-6) + prep (block 7) merged ----------------
__global__ __launch_bounds__(256)
void k_stats2prep(const float* __restrict__ pS, const float* __restrict__ pQ,
                  const float* __restrict__ w1, const float* __restrict__ b1,
                  const float* __restrict__ gam, const float* __restrict__ bet,
                  float* __restrict__ scale, float* __restrict__ shift,
                  const float* __restrict__ l2w, const float* __restrict__ l2b,
                  const float* __restrict__ lamr, const float* __restrict__ lami,
                  const float* __restrict__ bre, const float* __restrict__ bim,
                  const float* __restrict__ cre, const float* __restrict__ cim,
                  const float* __restrict__ dv,  const float* __restrict__ lstep,
                  float* __restrict__ gprm) {
    const int t = threadIdx.x;
    if (blockIdx.x < 7) {
        int l = blockIdx.x * 256 + t;
        if (l >= SEQ) return;
        float wm = 0, wq = 0, wb = 0, bm = 0, bq = 0;
        for (int h = 0; h < H; h++) {
            float w = w1[h], b = b1[h];
            wm += w; wq += w * w; wb += w * b; bm += b; bq += b * b;
        }
        const float inv = 1.f / 12.f;
        wm *= inv; wq *= inv; wb *= inv; bm *= inv; bq *= inv;
        float s = 0, q = 0;
        for (int k = 0; k < 16; k++) { s += pS[k * SEQ + l]; q += pQ[k * SEQ + l]; }
        float ex = s * (1.f / NB), exx = q * (1.f / NB);
        float mean = ex * wm + bm;
        float e2   = exx * wq + 2.f * ex * wb + bq;
        float var  = e2 - mean * mean;
        float sc   = gam[l] * rsqrtf(var + 1e-5f);
        scale[l] = sc;
        shift[l] = bet[l] - mean * sc;
        return;
    }
    // ---- block 7: derived parameters ----
    if (t < 48) {
        int h2 = t >> 3, p = t & 7, h = 2 * h2;
        gprm[O_C0R + 2 * t]     = 2.f * cre[h * PP + p];
        gprm[O_C0R + 2 * t + 1] = 2.f * cre[(h + 1) * PP + p];
        gprm[O_C0I + 2 * t]     = -2.f * cim[h * PP + p];
        gprm[O_C0I + 2 * t + 1] = -2.f * cim[(h + 1) * PP + p];
        gprm[O_C1R + 2 * t]     = 2.f * cre[96 + h * PP + p];
        gprm[O_C1R + 2 * t + 1] = 2.f * cre[96 + (h + 1) * PP + p];
        gprm[O_C1I + 2 * t]     = -2.f * cim[96 + h * PP + p];
        gprm[O_C1I + 2 * t + 1] = -2.f * cim[96 + (h + 1) * PP + p];
    }
    if (t < 6) {
        int h = 2 * t;
        gprm[O_FX0 + 2 * t] = w1[h] * dv[h];          gprm[O_FX0 + 2 * t + 1] = w1[h + 1] * dv[h + 1];
        gprm[O_FY0 + 2 * t] = b1[h] * dv[h];          gprm[O_FY0 + 2 * t + 1] = b1[h + 1] * dv[h + 1];
        gprm[O_FZ0 + 2 * t] = dv[h];                  gprm[O_FZ0 + 2 * t + 1] = dv[h + 1];
        gprm[O_FW0 + 2 * t] = w1[h] * dv[H + h];      gprm[O_FW0 + 2 * t + 1] = w1[h + 1] * dv[H + h + 1];
        gprm[O_F1X + 2 * t] = b1[h] * dv[H + h];      gprm[O_F1X + 2 * t + 1] = b1[h + 1] * dv[H + h + 1];
        gprm[O_F1Y + 2 * t] = dv[H + h];              gprm[O_F1Y + 2 * t + 1] = dv[H + h + 1];
        gprm[O_F1Z + 2 * t] = l2w[h] * dv[2 * H + h]; gprm[O_F1Z + 2 * t + 1] = l2w[h + 1] * dv[2 * H + h + 1];
    }
    if (t == 0) {
        float s0 = l2b[0], s1 = 0.f;
        for (int h = 0; h < H; h++) {
            float dw = l2w[h] * dv[2 * H + h];
            s0 += b1[h] * dw; s1 += w1[h] * dw;
        }
        gprm[O_SC + 0] = s0; gprm[O_SC + 1] = s1;
    }
    if (t < 24) {
        int L = t >> 3, p = t & 7;
        float stp = expf(lstep[L * PP + p]);
        float lr = lamr[L * PP + p], li = lami[L * PP + p];
        float er = expf(lr * stp);
        float lbr = er * cosf(li * stp), lbi = er * sinf(li * stp);   // lam_bar
        float p2r = lbr * lbr - lbi * lbi, p2i = 2.f * lbr * lbi;
        float p4r = p2r * p2r - p2i * p2i, p4i = 2.f * p2r * p2i;
        float p6r = p4r * p2r - p4i * p2i, p6i = p4r * p2i + p4i * p2r;
        float p7r = p6r * lbr - p6i * lbi, p7i = p6r * lbi + p6i * lbr;
        gprm[O_A6 + 2 * (L * PP + p) + 0] = p6r;
        gprm[O_A6 + 2 * (L * PP + p) + 1] = p6i;
        gprm[O_A7 + 2 * (L * PP + p) + 0] = p7r;
        gprm[O_A7 + 2 * (L * PP + p) + 1] = p7i;
        float den = lr * lr + li * li;
        float fr = ((lbr - 1.f) * lr + lbi * li) / den;
        float fi = (lbi * lr - (lbr - 1.f) * li) / den;
        float sAr = 0, sAi = 0, sBr = 0, sBi = 0, sCr = 0, sCi = 0;
        for (int h = 0; h < H; h++) {
            float brr = bre[L * 96 + p * H + h], bii = bim[L * 96 + p * H + h];
            float vr = fr * brr - fi * bii, vi = fr * bii + fi * brr;  // b_bar[p,h]
            float w = w1[h], bb = b1[h];
            sAr += w * vr; sAi += w * vi; sBr += bb * vr; sBi += bb * vi; sCr += vr; sCi += vi;
            int fidx = 2 * (h * PP + p);
            if (L == 1)      { gprm[O_BB1 + fidx] = vr; gprm[O_BB1 + fidx + 1] = vi; }
            else if (L == 2) { gprm[O_BB2 + fidx] = vr; gprm[O_BB2 + fidx + 1] = vi; }
        }
        if (L == 0) {
            gprm[O_G0A + 2 * p] = sAr; gprm[O_G0A + 2 * p + 1] = sAi;
            gprm[O_G0B + 2 * p] = sBr; gprm[O_G0B + 2 * p + 1] = sBi;
            gprm[O_G0C + 2 * p] = sCr; gprm[O_G0C + 2 * p + 1] = sCi;
            gprm[O_LB0R + 2 * p] = lbr; gprm[O_LB0R + 2 * p + 1] = lbr;
            gprm[O_LB0I + 2 * p] = lbi; gprm[O_LB0I + 2 * p + 1] = lbi;
        } else if (L == 1) {
            gprm[O_G1A + 2 * p] = sAr; gprm[O_G1A + 2 * p + 1] = sAi;
            gprm[O_G1B + 2 * p] = sBr; gprm[O_G1B + 2 * p + 1] = sBi;
            gprm[O_LB1R + 2 * p] = lbr; gprm[O_LB1R + 2 * p + 1] = lbr;
            gprm[O_LB1I + 2 * p] = lbi; gprm[O_LB1I + 2 * p + 1] = lbi;
        } else {
            gprm[O_G2A + 2 * p] = sAr; gprm[O_G2A + 2 * p + 1] = sAi;
            gprm[O_G2B + 2 * p] = sBr; gprm[O_G2B + 2 * p + 1] = sBi;
            gprm[O_LB2R + 2 * p] = lbr; gprm[O_LB2R + 2 * p + 1] = lbr;
            gprm[O_LB2I + 2 * p] = lbi; gprm[O_LB2I + 2 * p + 1] = lbi;
            float swr = 0, swi = 0;
            for (int hh = 0; hh < H; hh++) {
                float wv = l2w[hh];
                swr += wv * cre[192 + hh * PP + p];
                swi += wv * cim[192 + hh * PP + p];
            }
            gprm[O_CWN + 2 * p + 0] = 2.f * swr; gprm[O_CWN + 2 * p + 1] = -2.f * swi;
        }
    }
}

// ---- hierarchical carry scan across 256 threads (pk-packed combines) ----
__device__ __forceinline__ void scan_carry256(f2* S, const float2* a_init,
                                              int lane, int w,
                                              float2 (*aggA)[PP], float2 (*aggS)[PP]) {
    const f2 z2 = {0.f, 0.f};
    f2 A[PP];
#pragma unroll
    for (int p = 0; p < PP; p++) { A[p].x = a_init[p].x; A[p].y = a_init[p].y; }
#pragma unroll
    for (int d = 1; d < 64; d <<= 1) {
#pragma unroll
        for (int p = 0; p < PP; p++) {
            f2 fS, fA;
            fS.x = __shfl_up(S[p].x, (unsigned)d, 64);
            fS.y = __shfl_up(S[p].y, (unsigned)d, 64);
            fA.x = __shfl_up(A[p].x, (unsigned)d, 64);
            fA.y = __shfl_up(A[p].y, (unsigned)d, 64);
            if (lane >= d) {
                S[p] = cmulv(A[p], fS, S[p]);   // A_self (x) fS + S
                A[p] = cmulv(A[p], fA, z2);     // fA (x) A_self
            }
        }
    }
    __syncthreads();
    if (lane == 63) {
#pragma unroll
        for (int p = 0; p < PP; p++) {
            aggA[w][p] = make_float2(A[p].x, A[p].y);
            aggS[w][p] = make_float2(S[p].x, S[p].y);
        }
    }
    __syncthreads();
    float eSr[PP], eSi[PP], eAr[PP], eAi[PP];
#pragma unroll
    for (int p = 0; p < PP; p++) {
        float sr = __shfl_up(S[p].x, 1u, 64);
        float si = __shfl_up(S[p].y, 1u, 64);
        float ar = __shfl_up(A[p].x, 1u, 64);
        float ai = __shfl_up(A[p].y, 1u, 64);
        eSr[p] = (lane > 0) ? sr : 0.f;
        eSi[p] = (lane > 0) ? si : 0.f;
        eAr[p] = (lane > 0) ? ar : 1.f;
        eAi[p] = (lane > 0) ? ai : 0.f;
    }
    float Pr[PP], Pi[PP];
#pragma unroll
    for (int p = 0; p < PP; p++) { Pr[p] = 0.f; Pi[p] = 0.f; }
    for (int w2 = 0; w2 < w; w2++) {
#pragma unroll
        for (int p = 0; p < PP; p++) {
            float2 a = aggA[w2][p];
            float2 s = aggS[w2][p];
            float nr = a.x * Pr[p] - a.y * Pi[p] + s.x;
            float ni = a.x * Pi[p] + a.y * Pr[p] + s.y;
            Pr[p] = nr; Pi[p] = ni;
        }
    }
#pragma unroll
    for (int p = 0; p < PP; p++) {
        S[p].x = eAr[p] * Pr[p] - eAi[p] * Pi[p] + eSr[p];
        S[p].y = eAr[p] * Pi[p] + eAi[p] * Pr[p] + eSi[p];
    }
}

// ---------------- fully fused: 3 layers, h-pair packed fp32 ----------------
__global__ __launch_bounds__(256)
void k_main(const float* __restrict__ x,
            const float* __restrict__ gprm,
            const float* __restrict__ g_scale, const float* __restrict__ g_shift,
            float* __restrict__ out) {
    __shared__ float4 xq[SEQ];          // (xs, sc, sh, xx)
    __shared__ float2 aggA[4][PP], aggS[4][PP];
    const int tid = threadIdx.x, b = blockIdx.x;
    for (int i = tid; i < SEQ; i += 256) {
        float xx = x[(size_t)b * SEQ + i];
        float sc = g_scale[i], sh = g_shift[i];
        xq[i] = make_float4(xx * sc, sc, sh, xx);
    }
    __syncthreads();
    const f2* g0a = (const f2*)(gprm + O_G0A);
    const f2* g0b = (const f2*)(gprm + O_G0B);
    const f2* g0c = (const f2*)(gprm + O_G0C);
    const f2* g1a = (const f2*)(gprm + O_G1A);
    const f2* g1b = (const f2*)(gprm + O_G1B);
    const f2* g2a = (const f2*)(gprm + O_G2A);
    const f2* g2b = (const f2*)(gprm + O_G2B);
    const f2* lb0r = (const f2*)(gprm + O_LB0R);
    const f2* lb0i = (const f2*)(gprm + O_LB0I);
    const f2* lb1r = (const f2*)(gprm + O_LB1R);
    const f2* lb1i = (const f2*)(gprm + O_LB1I);
    const f2* lb2r = (const f2*)(gprm + O_LB2R);
    const f2* lb2i = (const f2*)(gprm + O_LB2I);
    const f2* c0r = (const f2*)(gprm + O_C0R);
    const f2* c0i = (const f2*)(gprm + O_C0I);
    const f2* c1r = (const f2*)(gprm + O_C1R);
    const f2* c1i = (const f2*)(gprm + O_C1I);
    const f2* bb1 = (const f2*)(gprm + O_BB1);
    const f2* bb2 = (const f2*)(gprm + O_BB2);
    const f2* fx0 = (const f2*)(gprm + O_FX0);
    const f2* fy0 = (const f2*)(gprm + O_FY0);
    const f2* fz0 = (const f2*)(gprm + O_FZ0);
    const f2* fw0 = (const f2*)(gprm + O_FW0);
    const f2* f1x = (const f2*)(gprm + O_F1X);
    const f2* f1y = (const f2*)(gprm + O_F1Y);
    const f2* f1z = (const f2*)(gprm + O_F1Z);
    const f2* cwn = (const f2*)(gprm + O_CWN);
    const float Sc0 = gprm[O_SC], Sc1 = gprm[O_SC + 1];
    const int w = tid >> 6, lane = tid & 63;
    const int len = (w == 3) ? 7 : 6;
    const int l0 = (w < 3) ? (w * 384 + lane * 6) : (1152 + lane * 7);
    const float2* aLb = (const float2*)(gprm + ((w == 3) ? O_A7 : O_A6));
    float* orow = out + (size_t)b * SEQ;
    const f2 z2 = {0.f, 0.f};

    f2 s0[PP], car0[PP];

    // ================= pass A: layer-0 local scan =================
#pragma unroll
    for (int p = 0; p < PP; p++) s0[p] = z2;
#pragma unroll 1
    for (int j = 0; j < len; j++) {
        float4 q = xq[l0 + j];
        float xs = q.x, sc = q.y, sh = q.z;
        f2 xs2 = {xs, xs}, sc2 = {sc, sc}, sh2 = {sh, sh};
#pragma unroll
        for (int p = 0; p < PP; p++) {
            f2 bu = pk_fma_s(g0c[p], sh2, z2);
            bu = pk_fma_s(g0b[p], sc2, bu);
            bu = pk_fma_s(g0a[p], xs2, bu);
            s0[p] = cfma_state(s0[p], lb0r[p], lb0i[p], bu);
        }
    }
    scan_carry256(s0, aLb, lane, w, aggA, aggS);
#pragma unroll
    for (int p = 0; p < PP; p++) car0[p] = s0[p];

    // ================= pass B: layer-0 exact + layer-1 local =================
    f2 s1[PP];
#pragma unroll
    for (int p = 0; p < PP; p++) s1[p] = z2;
#pragma unroll 1
    for (int j = 0; j < len; j++) {
        float4 q = xq[l0 + j];
        float xs = q.x, sc = q.y, sh = q.z, xx = q.w;
        f2 xs2 = {xs, xs}, sc2 = {sc, sc}, sh2 = {sh, sh}, xx2 = {xx, xx};
#pragma unroll
        for (int p = 0; p < PP; p++) {
            f2 bu = pk_fma_s(g0c[p], sh2, z2);
            bu = pk_fma_s(g0b[p], sc2, bu);
            bu = pk_fma_s(g0a[p], xs2, bu);
            s0[p] = cfma_state(s0[p], lb0r[p], lb0i[p], bu);
        }
        f2 r0p[6], t1[PP];
#pragma unroll
        for (int p = 0; p < PP; p++) t1[p] = z2;
#pragma unroll
        for (int h2 = 0; h2 < 6; h2++) {
            f2 acc = z2;
#pragma unroll
            for (int p = 0; p < PP; p++) {
                acc = pk_fma_s_blo(c0r[h2 * PP + p], s0[p], acc);
                acc = pk_fma_s_bhi(c0i[h2 * PP + p], s0[p], acc);
            }
            acc = pk_fma_s(fx0[h2], xs2, acc);
            acc = pk_fma_s(fy0[h2], sc2, acc);
            acc = pk_fma_s(fz0[h2], sh2, acc);
            acc.x = fmaxf(acc.x, 0.f); acc.y = fmaxf(acc.y, 0.f);
            r0p[h2] = acc;
#pragma unroll
            for (int p = 0; p < PP; p++) {
                t1[p] = pk_fma_s_blo(bb1[(2 * h2) * PP + p], acc, t1[p]);
                t1[p] = pk_fma_s_bhi(bb1[(2 * h2 + 1) * PP + p], acc, t1[p]);
            }
        }
#pragma unroll
        for (int p = 0; p < PP; p++) {
            f2 t = pk_fma_s(g1a[p], xx2, t1[p]);
            t = pk_add_s(g1b[p], t);
            s1[p] = cfma_state(s1[p], lb1r[p], lb1i[p], t);
        }
    }
    scan_carry256(s1, aLb + PP, lane, w, aggA, aggS);

    // ================= pass C: L0 exact + L1 exact + L2 local + out =================
    f2 s2[PP];
#pragma unroll
    for (int p = 0; p < PP; p++) { s0[p] = car0[p]; s2[p] = z2; }
#pragma unroll 1
    for (int j = 0; j < len; j++) {
        int l = l0 + j;
        float4 q = xq[l];
        float xs = q.x, sc = q.y, sh = q.z, xx = q.w;
        f2 xs2 = {xs, xs}, sc2 = {sc, sc}, sh2 = {sh, sh}, xx2 = {xx, xx};
#pragma unroll
        for (int p = 0; p < PP; p++) {
            f2 bu = pk_fma_s(g0c[p], sh2, z2);
            bu = pk_fma_s(g0b[p], sc2, bu);
            bu = pk_fma_s(g0a[p], xs2, bu);
            s0[p] = cfma_state(s0[p], lb0r[p], lb0i[p], bu);
        }
        f2 r0p[6], t1[PP];
#pragma unroll
        for (int p = 0; p < PP; p++) t1[p] = z2;
#pragma unroll
        for (int h2 = 0; h2 < 6; h2++) {
            f2 acc = z2;
#pragma unroll
            for (int p = 0; p < PP; p++) {
                acc = pk_fma_s_blo(c0r[h2 * PP + p], s0[p], acc);
                acc = pk_fma_s_bhi(c0i[h2 * PP + p], s0[p], acc);
            }
            acc = pk_fma_s(fx0[h2], xs2, acc);
            acc = pk_fma_s(fy0[h2], sc2, acc);
            acc = pk_fma_s(fz0[h2], sh2, acc);
            acc.x = fmaxf(acc.x, 0.f); acc.y = fmaxf(acc.y, 0.f);
            r0p[h2] = acc;
#pragma unroll
            for (int p = 0; p < PP; p++) {
                t1[p] = pk_fma_s_blo(bb1[(2 * h2) * PP + p], acc, t1[p]);
                t1[p] = pk_fma_s_bhi(bb1[(2 * h2 + 1) * PP + p], acc, t1[p]);
            }
        }
#pragma unroll
        for (int p = 0; p < PP; p++) {
            f2 t = pk_fma_s(g1a[p], xx2, t1[p]);
            t = pk_add_s(g1b[p], t);
            s1[p] = cfma_state(s1[p], lb1r[p], lb1i[p], t);
        }
        // layer 2: rs = r0 + relu(y1) consumed from reg pairs
        f2 t2[PP], op = z2;
#pragma unroll
        for (int p = 0; p < PP; p++) t2[p] = z2;
#pragma unroll
        for (int h2 = 0; h2 < 6; h2++) {
            f2 acc = z2;
#pragma unroll
            for (int p = 0; p < PP; p++) {
                acc = pk_fma_s_blo(c1r[h2 * PP + p], s1[p], acc);
                acc = pk_fma_s_bhi(c1i[h2 * PP + p], s1[p], acc);
            }
            acc = pk_fma_s(f1y[h2], r0p[h2], acc);
            acc = pk_fma_s(fw0[h2], xx2, acc);
            acc = pk_add_s(f1x[h2], acc);
            acc.x = fmaxf(acc.x, 0.f); acc.y = fmaxf(acc.y, 0.f);
            f2 rsp = pk_add_vv(r0p[h2], acc);
            op = pk_fma_s(f1z[h2], rsp, op);
#pragma unroll
            for (int p = 0; p < PP; p++) {
                t2[p] = pk_fma_s_blo(bb2[(2 * h2) * PP + p], rsp, t2[p]);
                t2[p] = pk_fma_s_bhi(bb2[(2 * h2 + 1) * PP + p], rsp, t2[p]);
            }
        }
#pragma unroll
        for (int p = 0; p < PP; p++) {
            f2 t = pk_fma_s(g2a[p], xx2, t2[p]);
            t = pk_add_s(g2b[p], t);
            s2[p] = cfma_state(s2[p], lb2r[p], lb2i[p], t);
        }
        f2 a2 = z2;
#pragma unroll
        for (int p = 0; p < PP; p++) a2 = pk_fma_s(cwn[p], s2[p], a2);
        orow[l] = Sc0 + xx * Sc1 + op.x + op.y + a2.x + a2.y;   // partial
    }
    scan_carry256(s2, aLb + 2 * PP, lane, w, aggA, aggS);  // -> carry2

    // fixup: out[l] += Re(lam2^{j+1} * (2*cw) . carry2)  — pk-packed
    f2 Tn[PP], m[PP];
#pragma unroll
    for (int p = 0; p < PP; p++) {
        float cwr = gprm[O_CWN + 2 * p], cwi = -gprm[O_CWN + 2 * p + 1];
        float trr = cwr * s2[p].x - cwi * s2[p].y;
        float tii = cwr * s2[p].y + cwi * s2[p].x;
        Tn[p].x = trr; Tn[p].y = -tii;       // (Tr, -Ti): Re(m.T) = m . Tn
        m[p].x = gprm[O_LB2R + 2 * p];
        m[p].y = gprm[O_LB2I + 2 * p];       // lam2
    }
#pragma unroll 1
    for (int j = 0; j < len; j++) {
        f2 cacc = z2;
#pragma unroll
        for (int p = 0; p < PP; p++) cacc = pk_fma_vv(m[p], Tn[p], cacc);
        orow[l0 + j] += cacc.x + cacc.y;
#pragma unroll
        for (int p = 0; p < PP; p++)
            m[p] = cfma_state(m[p], lb2r[p], lb2i[p], z2);   // m *= lam2
    }
}

extern "C" void kernel_launch(void* const* d_in, const int* in_sizes, int n_in,
                              void* d_out, int out_size, void* d_ws, size_t ws_size,
                              hipStream_t stream) {
    const float* x     = (const float*)d_in[0];
    const float* l1w   = (const float*)d_in[1];
    const float* l1b   = (const float*)d_in[2];
    const float* l2w   = (const float*)d_in[3];
    const float* l2b   = (const float*)d_in[4];
    const float* gam   = (const float*)d_in[5];
    const float* bet   = (const float*)d_in[6];
    const float* lamr  = (const float*)d_in[7];
    const float* lami  = (const float*)d_in[8];
    const float* bre   = (const float*)d_in[9];
    const float* bim   = (const float*)d_in[10];
    const float* cre   = (const float*)d_in[11];
    const float* cim   = (const float*)d_in[12];
    const float* dv    = (const float*)d_in[13];
    const float* lstep = (const float*)d_in[14];
    float* out = (float*)d_out;

    float* wsf     = (float*)d_ws;
    float* w_scale = wsf;                  // 1600
    float* w_shift = wsf + SEQ;            // 1600
    float* pS      = wsf + 2 * SEQ;        // 16*1600
    float* pQ      = pS + 16 * SEQ;        // 16*1600
    float* gprm    = pQ + 16 * SEQ;        // PRMF (padded to 1280)

    k_stats1<<<dim3(7, 16), 256, 0, stream>>>(x, pS, pQ);
    k_stats2prep<<<dim3(8), 256, 0, stream>>>(pS, pQ, l1w, l1b, gam, bet,
                                              w_scale, w_shift,
                                              l2w, l2b, lamr, lami,
                                              bre, bim, cre, cim, dv, lstep, gprm);
    k_main<<<dim3(NB), 256, 0, stream>>>(x, gprm, w_scale, w_shift, out);
}